// Round 5
// baseline (81.882 us; speedup 1.0000x reference)
//
#include <hip/hip_runtime.h>

// Problem: B=4, N=512, D=256, H=256, M = B*N = 2048
// out[b,i,j] = 0.5*(E + E^T),  E[b,i,j] = sum_h v[h]*tanh(Q[b,i,h]+K[b,j,h])
// tanh(q+k) = 1 - 2/(1+e^{2q}e^{2k}); u=exp2(C2*q), w=exp2(C2*k), C2=2*log2(e)
// P_ij = sum_h v_h/(1+u_ih w_jh);  out_ij = Sv - (P_ij + P_ji)
// 2-way rcp batching: v0/A0 + v1/A1 = (v0*A1 + v1*A0)/(A0*A1), A_t = 1+u_t w_t.
//   u,w clamped <= 1e4 in gemm3 epilogue -> A <= 1e8+1, A0*A1 <= ~1e16 (safe).
// GEMM fold: Q = h1 @ (Wq@W2)^T + (Wq@b2+bq)  (no activation between fc2, Q/K)

typedef float f2 __attribute__((ext_vector_type(2)));
typedef float f4 __attribute__((ext_vector_type(4)));
typedef float f32x4 __attribute__((ext_vector_type(4)));
typedef __bf16 bf16x8 __attribute__((ext_vector_type(8)));

#define C2F 2.8853900817779268f

__device__ inline unsigned short f2bf(float f) {
    unsigned u = __float_as_uint(f);
    unsigned r = (u + 0x7fffu + ((u >> 16) & 1u)) >> 16;
    return (unsigned short)r;
}
__device__ inline float bf2f(unsigned short h) {
    return __uint_as_float(((unsigned)h) << 16);
}

__device__ inline void split4(const f4 a, unsigned short* hp, unsigned short* lp) {
    unsigned short h[4], l[4];
#pragma unroll
    for (int t = 0; t < 4; ++t) {
        h[t] = f2bf(a[t]);
        l[t] = f2bf(a[t] - bf2f(h[t]));
    }
    uint2 hv, lv;
    hv.x = (unsigned)h[0] | ((unsigned)h[1] << 16);
    hv.y = (unsigned)h[2] | ((unsigned)h[3] << 16);
    lv.x = (unsigned)l[0] | ((unsigned)l[1] << 16);
    lv.y = (unsigned)l[2] | ((unsigned)l[3] << 16);
    *(uint2*)hp = hv;
    *(uint2*)lp = lv;
}

// ---------------------------------------------------------------------------
// gemm_fullk: C[m,n] = act( sum_k A[m,k]*Wsel[n,k] + bias[n] ), K=256 resident.
// ACT: 1=tanh, 2=exp2(C2*x) clamped to [0,1e4]
// ---------------------------------------------------------------------------
template <int ACT>
__global__ __launch_bounds__(256) void gemm_fullk(
    const float* __restrict__ A, const float* __restrict__ Wa,
    const float* __restrict__ Wb, const float* __restrict__ ba,
    const float* __restrict__ bb2, float* __restrict__ C, int Nn) {
    __shared__ unsigned short sAhi[64][264];
    __shared__ unsigned short sAlo[64][264];
    __shared__ unsigned short sBhi[64][264];
    __shared__ unsigned short sBlo[64][264];

    const int tid = threadIdx.x;
    const int m0 = blockIdx.x << 6;
    const int n0 = blockIdx.y << 6;

    const float* Atile = A + (size_t)m0 * 256;
    const float* Wtile = (n0 < 256) ? (Wa + (size_t)n0 * 256)
                                    : (Wb + (size_t)(n0 - 256) * 256);
    const int col4 = (tid & 63) << 2;
    const int rgrp = tid >> 6;
#pragma unroll
    for (int t = 0; t < 16; ++t) {
        const int row = (t << 2) + rgrp;
        f4 av = *(const f4*)&Atile[(size_t)row * 256 + col4];
        f4 wv = *(const f4*)&Wtile[(size_t)row * 256 + col4];
        split4(av, &sAhi[row][col4], &sAlo[row][col4]);
        split4(wv, &sBhi[row][col4], &sBlo[row][col4]);
    }
    __syncthreads();

    const int lane = tid & 63;
    const int wav = tid >> 6;
    const int wm = wav >> 1, wn = wav & 1;
    const int fr = lane & 15;
    const int fks = (lane >> 4) << 3;

    f32x4 acc[2][2];
#pragma unroll
    for (int i = 0; i < 2; ++i)
#pragma unroll
        for (int j = 0; j < 2; ++j) acc[i][j] = (f32x4){0.f, 0.f, 0.f, 0.f};

#pragma unroll
    for (int kt = 0; kt < 256; kt += 32) {
        bf16x8 ah[2], al[2], bh[2], bl[2];
#pragma unroll
        for (int s = 0; s < 2; ++s) {
            ah[s] = *(const bf16x8*)&sAhi[(wm << 5) + (s << 4) + fr][kt + fks];
            al[s] = *(const bf16x8*)&sAlo[(wm << 5) + (s << 4) + fr][kt + fks];
            bh[s] = *(const bf16x8*)&sBhi[(wn << 5) + (s << 4) + fr][kt + fks];
            bl[s] = *(const bf16x8*)&sBlo[(wn << 5) + (s << 4) + fr][kt + fks];
        }
#pragma unroll
        for (int i = 0; i < 2; ++i)
#pragma unroll
            for (int j = 0; j < 2; ++j) {
                acc[i][j] = __builtin_amdgcn_mfma_f32_16x16x32_bf16(ah[i], bh[j], acc[i][j], 0, 0, 0);
                acc[i][j] = __builtin_amdgcn_mfma_f32_16x16x32_bf16(ah[i], bl[j], acc[i][j], 0, 0, 0);
                acc[i][j] = __builtin_amdgcn_mfma_f32_16x16x32_bf16(al[i], bh[j], acc[i][j], 0, 0, 0);
            }
    }

    const int rbase = (lane >> 4) << 2;
#pragma unroll
    for (int i = 0; i < 2; ++i) {
#pragma unroll
        for (int j = 0; j < 2; ++j) {
            const int gcol = n0 + (wn << 5) + (j << 4) + fr;
            const float bias = (ACT == 2 && gcol >= 256) ? bb2[gcol - 256] : ba[gcol];
#pragma unroll
            for (int q = 0; q < 4; ++q) {
                const int grow = m0 + (wm << 5) + (i << 4) + rbase + q;
                float x = acc[i][j][q] + bias;
                if (ACT == 1)
                    x = 1.0f - 2.0f * __builtin_amdgcn_rcpf(
                                          1.0f + __builtin_amdgcn_exp2f(C2F * x));
                if (ACT == 2)
                    x = fminf(__builtin_amdgcn_exp2f(C2F * x), 1.0e4f);
                C[(size_t)grow * Nn + gcol] = x;
            }
        }
    }
}

// ---------------------------------------------------------------------------
// gemm_stage1: fused launch.
//  blocks [0,128): h1 = tanh(X @ W1^T + b1)
//  blocks [128,160): Wc = [Wq;Wk] @ W2 (B not transp.), bc = Asel@b2 + bias
// ---------------------------------------------------------------------------
__global__ __launch_bounds__(256) void gemm_stage1(
    const float* __restrict__ X, const float* __restrict__ W1,
    const float* __restrict__ b1, const float* __restrict__ Wq,
    const float* __restrict__ Wk, const float* __restrict__ W2,
    const float* __restrict__ b2, const float* __restrict__ bq,
    const float* __restrict__ bk, float* __restrict__ h1,
    float* __restrict__ Wc, float* __restrict__ bc) {
    __shared__ unsigned short sAhi[64][264];
    __shared__ unsigned short sAlo[64][264];
    __shared__ unsigned short sBhi[64][264];
    __shared__ unsigned short sBlo[64][264];
    __shared__ float sred[64][4];

    const int tid = threadIdx.x;
    const bool is_nt = (blockIdx.x >= 128);
    const int blk = is_nt ? (blockIdx.x - 128) : blockIdx.x;
    const int m0 = (blk >> 2) << 6;
    const int n0 = (blk & 3) << 6;

    const int col4 = (tid & 63) << 2;
    const int rgrp = tid >> 6;

    if (!is_nt) {
        const float* Atile = X + (size_t)m0 * 256;
        const float* Wtile = W1 + (size_t)n0 * 256;
#pragma unroll
        for (int t = 0; t < 16; ++t) {
            const int row = (t << 2) + rgrp;
            f4 av = *(const f4*)&Atile[(size_t)row * 256 + col4];
            f4 wv = *(const f4*)&Wtile[(size_t)row * 256 + col4];
            split4(av, &sAhi[row][col4], &sAlo[row][col4]);
            split4(wv, &sBhi[row][col4], &sBlo[row][col4]);
        }
    } else {
        const float* Atile = (m0 < 256) ? (Wq + (size_t)m0 * 256)
                                        : (Wk + (size_t)(m0 - 256) * 256);
#pragma unroll
        for (int t = 0; t < 16; ++t) {
            const int row = (t << 2) + rgrp;
            f4 av = *(const f4*)&Atile[(size_t)row * 256 + col4];
            split4(av, &sAhi[row][col4], &sAlo[row][col4]);
        }
        const int c4 = (tid & 15) << 2;
        const int kg = tid >> 4;
#pragma unroll
        for (int t = 0; t < 16; ++t) {
            const int k = (t << 4) + kg;
            f4 wv = *(const f4*)&W2[(size_t)k * 256 + n0 + c4];
#pragma unroll
            for (int q = 0; q < 4; ++q) {
                unsigned short hi = f2bf(wv[q]);
                sBhi[c4 + q][k] = hi;
                sBlo[c4 + q][k] = f2bf(wv[q] - bf2f(hi));
            }
        }
    }
    __syncthreads();

    const int lane = tid & 63;
    const int wav = tid >> 6;
    const int wm = wav >> 1, wn = wav & 1;
    const int fr = lane & 15;
    const int fks = (lane >> 4) << 3;

    f32x4 acc[2][2];
#pragma unroll
    for (int i = 0; i < 2; ++i)
#pragma unroll
        for (int j = 0; j < 2; ++j) acc[i][j] = (f32x4){0.f, 0.f, 0.f, 0.f};

#pragma unroll
    for (int kt = 0; kt < 256; kt += 32) {
        bf16x8 ah[2], al[2], bh[2], bl[2];
#pragma unroll
        for (int s = 0; s < 2; ++s) {
            ah[s] = *(const bf16x8*)&sAhi[(wm << 5) + (s << 4) + fr][kt + fks];
            al[s] = *(const bf16x8*)&sAlo[(wm << 5) + (s << 4) + fr][kt + fks];
            bh[s] = *(const bf16x8*)&sBhi[(wn << 5) + (s << 4) + fr][kt + fks];
            bl[s] = *(const bf16x8*)&sBlo[(wn << 5) + (s << 4) + fr][kt + fks];
        }
#pragma unroll
        for (int i = 0; i < 2; ++i)
#pragma unroll
            for (int j = 0; j < 2; ++j) {
                acc[i][j] = __builtin_amdgcn_mfma_f32_16x16x32_bf16(ah[i], bh[j], acc[i][j], 0, 0, 0);
                acc[i][j] = __builtin_amdgcn_mfma_f32_16x16x32_bf16(ah[i], bl[j], acc[i][j], 0, 0, 0);
                acc[i][j] = __builtin_amdgcn_mfma_f32_16x16x32_bf16(al[i], bh[j], acc[i][j], 0, 0, 0);
            }
    }

    const int rbase = (lane >> 4) << 2;
    if (!is_nt) {
#pragma unroll
        for (int i = 0; i < 2; ++i)
#pragma unroll
            for (int j = 0; j < 2; ++j) {
                const int gcol = n0 + (wn << 5) + (j << 4) + fr;
                const float bias = b1[gcol];
#pragma unroll
                for (int q = 0; q < 4; ++q) {
                    const int grow = m0 + (wm << 5) + (i << 4) + rbase + q;
                    float x = acc[i][j][q] + bias;
                    x = 1.0f - 2.0f * __builtin_amdgcn_rcpf(
                                          1.0f + __builtin_amdgcn_exp2f(C2F * x));
                    h1[(size_t)grow * 256 + gcol] = x;
                }
            }
    } else {
#pragma unroll
        for (int i = 0; i < 2; ++i)
#pragma unroll
            for (int j = 0; j < 2; ++j) {
                const int gcol = n0 + (wn << 5) + (j << 4) + fr;
#pragma unroll
                for (int q = 0; q < 4; ++q) {
                    const int grow = m0 + (wm << 5) + (i << 4) + rbase + q;
                    Wc[(size_t)grow * 256 + gcol] = acc[i][j][q];
                }
            }
        if ((blk & 3) == 0) {
            const int rr = tid >> 2;
            const int part = (tid & 3) << 6;
            const int grow = m0 + rr;
            const float* Ar = (grow < 256) ? &Wq[(size_t)grow * 256]
                                           : &Wk[(size_t)(grow - 256) * 256];
            float s = 0.f;
#pragma unroll
            for (int e = 0; e < 64; e += 4) {
                f4 a = *(const f4*)&Ar[part + e];
                f4 bv = *(const f4*)&b2[part + e];
                s += a[0] * bv[0] + a[1] * bv[1] + a[2] * bv[2] + a[3] * bv[3];
            }
            sred[rr][tid & 3] = s;
            __syncthreads();
            if (tid < 64) {
                float bias = sred[tid][0] + sred[tid][1] + sred[tid][2] + sred[tid][3];
                const int g2 = m0 + tid;
                bias += (g2 < 256) ? bq[g2] : bk[g2 - 256];
                bc[g2] = bias;
            }
        }
    }
}

// ---------------------------------------------------------------------------
// pairwise: per (b, i-tile, j-tile, h-chunk) block writes
//   Ep[chunk][b,i,j] = sum_{h in 64-chunk} v_h/(1+u_ih w_jh)
// 512 thr, 64x64 tile, ONE 64-h chunk per block (35 KB LDS -> 4 blocks/CU,
// 8 waves/SIMD).  2-way rcp batching.
// ---------------------------------------------------------------------------
__global__ __launch_bounds__(512, 8) void pairwise_kernel(
    const float* __restrict__ uwb, const float* __restrict__ v,
    float* __restrict__ Ep) {
    __shared__ float sU[64][68];
    __shared__ float sW[64][68];
    __shared__ float sV[64];

    const int tid = threadIdx.x;
    const int bb = blockIdx.x;       // 1024 = (4b * 64 tiles) * 4 h-chunks
    const int hcs = bb & 3;          // h-chunk slice index
    const int hc = hcs << 6;
    const int tt = bb >> 2;
    const int b = tt >> 6;
    const int i0 = ((tt >> 3) & 7) << 6;
    const int j0 = (tt & 7) << 6;

    const float* ubase = uwb + (size_t)((b << 9) + i0) * 512 + hc;
    const float* wbase = uwb + (size_t)((b << 9) + j0) * 512 + 256 + hc;

    const int sr = tid >> 3;         // 0..63
    const int sc = (tid & 7) << 3;   // 0,8,..,56
    {
        f4 a0 = *(const f4*)&ubase[(size_t)sr * 512 + sc];
        f4 a1 = *(const f4*)&ubase[(size_t)sr * 512 + sc + 4];
        f4 b0 = *(const f4*)&wbase[(size_t)sr * 512 + sc];
        f4 b1 = *(const f4*)&wbase[(size_t)sr * 512 + sc + 4];
        *(f4*)&sU[sr][sc] = a0;
        *(f4*)&sU[sr][sc + 4] = a1;
        *(f4*)&sW[sr][sc] = b0;
        *(f4*)&sW[sr][sc + 4] = b1;
    }
    if (tid < 16) *(f4*)&sV[tid << 2] = *(const f4*)&v[hc + (tid << 2)];
    __syncthreads();

    const int ty = tid >> 5;   // 0..15: rows ty+16d
    const int tx = tid & 31;   // 0..31: cols tx+32e

    float acc[4][2];
#pragma unroll
    for (int d = 0; d < 4; ++d)
#pragma unroll
        for (int e = 0; e < 2; ++e) acc[d][e] = 0.f;

    const f2 one2 = (f2){1.f, 1.f};

#pragma unroll 4
    for (int h4 = 0; h4 < 64; h4 += 4) {
        f4 vv = *(const f4*)&sV[h4];
        f4 uu[4], ww[2];
#pragma unroll
        for (int d = 0; d < 4; ++d) uu[d] = *(const f4*)&sU[ty + (d << 4)][h4];
#pragma unroll
        for (int e = 0; e < 2; ++e) ww[e] = *(const f4*)&sW[tx + (e << 5)][h4];
#pragma unroll
        for (int d = 0; d < 4; ++d)
#pragma unroll
            for (int e = 0; e < 2; ++e) {
                f2 u01 = (f2){uu[d][0], uu[d][1]};
                f2 u23 = (f2){uu[d][2], uu[d][3]};
                f2 w01 = (f2){ww[e][0], ww[e][1]};
                f2 w23 = (f2){ww[e][2], ww[e][3]};
                f2 A01 = __builtin_elementwise_fma(u01, w01, one2);
                f2 A23 = __builtin_elementwise_fma(u23, w23, one2);
                float m01 = A01.x * A01.y;
                float t01 = fmaf(vv[0], A01.y, vv[1] * A01.x);
                acc[d][e] = fmaf(t01, __builtin_amdgcn_rcpf(m01), acc[d][e]);
                float m23 = A23.x * A23.y;
                float t23 = fmaf(vv[2], A23.y, vv[3] * A23.x);
                acc[d][e] = fmaf(t23, __builtin_amdgcn_rcpf(m23), acc[d][e]);
            }
    }

    float* ep = Ep + (size_t)hcs * 1048576 + (size_t)((b << 9) + i0) * 512 + j0;
#pragma unroll
    for (int d = 0; d < 4; ++d)
#pragma unroll
        for (int e = 0; e < 2; ++e)
            ep[(size_t)(ty + (d << 4)) * 512 + tx + (e << 5)] = acc[d][e];
}

// out[b,i,j] = Sv - sum_s Ep_s[b,i,j] - sum_s Ep_s[b,j,i]
__global__ __launch_bounds__(256) void sym_kernel(const float* __restrict__ Ep,
                                                  const float* __restrict__ v,
                                                  float* __restrict__ out) {
    __shared__ float t1[64][65];
    __shared__ float t2[64][65];
    __shared__ float red[4];

    const int tid = threadIdx.x;
    const int lane = tid & 63, wv = tid >> 6;

    float x = v[tid];
#pragma unroll
    for (int o = 32; o > 0; o >>= 1) x += __shfl_xor(x, o, 64);
    if (lane == 0) red[wv] = x;

    const int bb = blockIdx.x;
    const int b = bb >> 6;
    const int i0 = ((bb >> 3) & 7) << 6;
    const int j0 = (bb & 7) << 6;

    for (int idx = tid; idx < 4096; idx += 256) {
        const int r = idx >> 6, c = idx & 63;
        const size_t o1 = (size_t)((b << 9) + i0 + r) * 512 + j0 + c;
        const size_t o2 = (size_t)((b << 9) + j0 + r) * 512 + i0 + c;
        t1[r][c] = (Ep[o1] + Ep[o1 + 1048576]) +
                   (Ep[o1 + 2097152] + Ep[o1 + 3145728]);
        t2[r][c] = (Ep[o2] + Ep[o2 + 1048576]) +
                   (Ep[o2 + 2097152] + Ep[o2 + 3145728]);
    }
    __syncthreads();
    const float Sv = red[0] + red[1] + red[2] + red[3];
    for (int idx = tid; idx < 4096; idx += 256) {
        const int r = idx >> 6, c = idx & 63;
        out[(size_t)((b << 9) + i0 + r) * 512 + j0 + c] = Sv - (t1[r][c] + t2[c][r]);
    }
}

extern "C" void kernel_launch(void* const* d_in, const int* in_sizes, int n_in,
                              void* d_out, int out_size, void* d_ws, size_t ws_size,
                              hipStream_t stream) {
    const float* X  = (const float*)d_in[0];
    // d_in[1] = Y (unused)
    const float* W1 = (const float*)d_in[2];
    const float* b1 = (const float*)d_in[3];
    const float* W2 = (const float*)d_in[4];
    const float* b2 = (const float*)d_in[5];
    const float* Wq = (const float*)d_in[6];
    const float* bq = (const float*)d_in[7];
    const float* Wk = (const float*)d_in[8];
    const float* bk = (const float*)d_in[9];
    const float* v  = (const float*)d_in[10];
    // d_in[11] = k (unused)

    float* ws  = (float*)d_ws;
    float* h1  = ws;                 // 2048*256 = 524288 f
    float* uwb = ws + 524288;        // 2048*512 = 1048576 f
    float* Wc  = ws + 1572864;       // 512*256  = 131072 f
    float* bc  = ws + 1703936;       // 512 f
    float* Ep  = ws + 1704448;       // 4*1048576 f
    float* out = (float*)d_out;

    // fused: h1 = tanh(X@W1^T+b1)  and  Wc = [Wq;Wk]@W2, bc = [..]@b2 + bias
    gemm_stage1<<<160, 256, 0, stream>>>(X, W1, b1, Wq, Wk, W2, b2, bq, bk,
                                         h1, Wc, bc);
    // uwb[:, :256] = min(exp2(C2*Q),1e4), uwb[:, 256:] = min(exp2(C2*K),1e4)
    gemm_fullk<2><<<dim3(32, 8), 256, 0, stream>>>(h1, Wc, Wc + 65536, bc,
                                                   bc + 256, uwb, 512);
    // Ep[hc][b,i,j] = sum_{h in chunk} v_h/(1+u w)
    pairwise_kernel<<<1024, 512, 0, stream>>>(uwb, v, Ep);
    // out = Sv - sum(Ep) - sum(Ep)^T
    sym_kernel<<<256, 256, 0, stream>>>(Ep, v, out);
}

// Round 6
// 65.485 us; speedup vs baseline: 1.2504x; 1.2504x over previous
//
#include <hip/hip_runtime.h>

// Problem: B=4, N=512, D=256, H=256, M = B*N = 2048
// out[b,i,j] = 0.5*(E + E^T),  E[b,i,j] = sum_h v[h]*tanh(Q[b,i,h]+K[b,j,h])
// tanh(q+k) = 1 - 2/(1+e^{2q}e^{2k}); u=exp2(C2*q), w=exp2(C2*k), C2=2*log2(e)
// P_ij = sum_h v_h/(1+u_ih w_jh);  out_ij = Sv - (P_ij + P_ji)
// 2-way rcp batching: v0/A0 + v1/A1 = (v0*A1 + v1*A0)/(A0*A1), A_t = 1+u_t w_t.
//   u,w clamped <= 1e4 in gemm3 epilogue -> A <= 1e8+1, A0*A1 <= ~1e16 (safe).
// GEMM fold: Q = h1 @ (Wq@W2)^T + (Wq@b2+bq)  (no activation between fc2, Q/K)

typedef float f2 __attribute__((ext_vector_type(2)));
typedef float f4 __attribute__((ext_vector_type(4)));
typedef float f32x4 __attribute__((ext_vector_type(4)));
typedef __bf16 bf16x8 __attribute__((ext_vector_type(8)));

#define C2F 2.8853900817779268f

__device__ inline unsigned short f2bf(float f) {
    unsigned u = __float_as_uint(f);
    unsigned r = (u + 0x7fffu + ((u >> 16) & 1u)) >> 16;
    return (unsigned short)r;
}
__device__ inline float bf2f(unsigned short h) {
    return __uint_as_float(((unsigned)h) << 16);
}

__device__ inline void split4(const f4 a, unsigned short* hp, unsigned short* lp) {
    unsigned short h[4], l[4];
#pragma unroll
    for (int t = 0; t < 4; ++t) {
        h[t] = f2bf(a[t]);
        l[t] = f2bf(a[t] - bf2f(h[t]));
    }
    uint2 hv, lv;
    hv.x = (unsigned)h[0] | ((unsigned)h[1] << 16);
    hv.y = (unsigned)h[2] | ((unsigned)h[3] << 16);
    lv.x = (unsigned)l[0] | ((unsigned)l[1] << 16);
    lv.y = (unsigned)l[2] | ((unsigned)l[3] << 16);
    *(uint2*)hp = hv;
    *(uint2*)lp = lv;
}

// ---------------------------------------------------------------------------
// gemm_fullk: C[m,n] = act( sum_k A[m,k]*Wsel[n,k] + bias[n] ), K=256 resident.
// ACT: 1=tanh, 2=exp2(C2*x) clamped to [0,1e4]
// ---------------------------------------------------------------------------
template <int ACT>
__global__ __launch_bounds__(256) void gemm_fullk(
    const float* __restrict__ A, const float* __restrict__ Wa,
    const float* __restrict__ Wb, const float* __restrict__ ba,
    const float* __restrict__ bb2, float* __restrict__ C, int Nn) {
    __shared__ unsigned short sAhi[64][264];
    __shared__ unsigned short sAlo[64][264];
    __shared__ unsigned short sBhi[64][264];
    __shared__ unsigned short sBlo[64][264];

    const int tid = threadIdx.x;
    const int m0 = blockIdx.x << 6;
    const int n0 = blockIdx.y << 6;

    const float* Atile = A + (size_t)m0 * 256;
    const float* Wtile = (n0 < 256) ? (Wa + (size_t)n0 * 256)
                                    : (Wb + (size_t)(n0 - 256) * 256);
    const int col4 = (tid & 63) << 2;
    const int rgrp = tid >> 6;
#pragma unroll
    for (int t = 0; t < 16; ++t) {
        const int row = (t << 2) + rgrp;
        f4 av = *(const f4*)&Atile[(size_t)row * 256 + col4];
        f4 wv = *(const f4*)&Wtile[(size_t)row * 256 + col4];
        split4(av, &sAhi[row][col4], &sAlo[row][col4]);
        split4(wv, &sBhi[row][col4], &sBlo[row][col4]);
    }
    __syncthreads();

    const int lane = tid & 63;
    const int wav = tid >> 6;
    const int wm = wav >> 1, wn = wav & 1;
    const int fr = lane & 15;
    const int fks = (lane >> 4) << 3;

    f32x4 acc[2][2];
#pragma unroll
    for (int i = 0; i < 2; ++i)
#pragma unroll
        for (int j = 0; j < 2; ++j) acc[i][j] = (f32x4){0.f, 0.f, 0.f, 0.f};

#pragma unroll
    for (int kt = 0; kt < 256; kt += 32) {
        bf16x8 ah[2], al[2], bh[2], bl[2];
#pragma unroll
        for (int s = 0; s < 2; ++s) {
            ah[s] = *(const bf16x8*)&sAhi[(wm << 5) + (s << 4) + fr][kt + fks];
            al[s] = *(const bf16x8*)&sAlo[(wm << 5) + (s << 4) + fr][kt + fks];
            bh[s] = *(const bf16x8*)&sBhi[(wn << 5) + (s << 4) + fr][kt + fks];
            bl[s] = *(const bf16x8*)&sBlo[(wn << 5) + (s << 4) + fr][kt + fks];
        }
#pragma unroll
        for (int i = 0; i < 2; ++i)
#pragma unroll
            for (int j = 0; j < 2; ++j) {
                acc[i][j] = __builtin_amdgcn_mfma_f32_16x16x32_bf16(ah[i], bh[j], acc[i][j], 0, 0, 0);
                acc[i][j] = __builtin_amdgcn_mfma_f32_16x16x32_bf16(ah[i], bl[j], acc[i][j], 0, 0, 0);
                acc[i][j] = __builtin_amdgcn_mfma_f32_16x16x32_bf16(al[i], bh[j], acc[i][j], 0, 0, 0);
            }
    }

    const int rbase = (lane >> 4) << 2;
#pragma unroll
    for (int i = 0; i < 2; ++i) {
#pragma unroll
        for (int j = 0; j < 2; ++j) {
            const int gcol = n0 + (wn << 5) + (j << 4) + fr;
            const float bias = (ACT == 2 && gcol >= 256) ? bb2[gcol - 256] : ba[gcol];
#pragma unroll
            for (int q = 0; q < 4; ++q) {
                const int grow = m0 + (wm << 5) + (i << 4) + rbase + q;
                float x = acc[i][j][q] + bias;
                if (ACT == 1)
                    x = 1.0f - 2.0f * __builtin_amdgcn_rcpf(
                                          1.0f + __builtin_amdgcn_exp2f(C2F * x));
                if (ACT == 2)
                    x = fminf(__builtin_amdgcn_exp2f(C2F * x), 1.0e4f);
                C[(size_t)grow * Nn + gcol] = x;
            }
        }
    }
}

// ---------------------------------------------------------------------------
// gemm_stage1: fused launch.
//  blocks [0,128): h1 = tanh(X @ W1^T + b1)
//  blocks [128,160): Wc = [Wq;Wk] @ W2 (B not transp.), bc = Asel@b2 + bias
// ---------------------------------------------------------------------------
__global__ __launch_bounds__(256) void gemm_stage1(
    const float* __restrict__ X, const float* __restrict__ W1,
    const float* __restrict__ b1, const float* __restrict__ Wq,
    const float* __restrict__ Wk, const float* __restrict__ W2,
    const float* __restrict__ b2, const float* __restrict__ bq,
    const float* __restrict__ bk, float* __restrict__ h1,
    float* __restrict__ Wc, float* __restrict__ bc) {
    __shared__ unsigned short sAhi[64][264];
    __shared__ unsigned short sAlo[64][264];
    __shared__ unsigned short sBhi[64][264];
    __shared__ unsigned short sBlo[64][264];
    __shared__ float sred[64][4];

    const int tid = threadIdx.x;
    const bool is_nt = (blockIdx.x >= 128);
    const int blk = is_nt ? (blockIdx.x - 128) : blockIdx.x;
    const int m0 = (blk >> 2) << 6;
    const int n0 = (blk & 3) << 6;

    const int col4 = (tid & 63) << 2;
    const int rgrp = tid >> 6;

    if (!is_nt) {
        const float* Atile = X + (size_t)m0 * 256;
        const float* Wtile = W1 + (size_t)n0 * 256;
#pragma unroll
        for (int t = 0; t < 16; ++t) {
            const int row = (t << 2) + rgrp;
            f4 av = *(const f4*)&Atile[(size_t)row * 256 + col4];
            f4 wv = *(const f4*)&Wtile[(size_t)row * 256 + col4];
            split4(av, &sAhi[row][col4], &sAlo[row][col4]);
            split4(wv, &sBhi[row][col4], &sBlo[row][col4]);
        }
    } else {
        const float* Atile = (m0 < 256) ? (Wq + (size_t)m0 * 256)
                                        : (Wk + (size_t)(m0 - 256) * 256);
#pragma unroll
        for (int t = 0; t < 16; ++t) {
            const int row = (t << 2) + rgrp;
            f4 av = *(const f4*)&Atile[(size_t)row * 256 + col4];
            split4(av, &sAhi[row][col4], &sAlo[row][col4]);
        }
        const int c4 = (tid & 15) << 2;
        const int kg = tid >> 4;
#pragma unroll
        for (int t = 0; t < 16; ++t) {
            const int k = (t << 4) + kg;
            f4 wv = *(const f4*)&W2[(size_t)k * 256 + n0 + c4];
#pragma unroll
            for (int q = 0; q < 4; ++q) {
                unsigned short hi = f2bf(wv[q]);
                sBhi[c4 + q][k] = hi;
                sBlo[c4 + q][k] = f2bf(wv[q] - bf2f(hi));
            }
        }
    }
    __syncthreads();

    const int lane = tid & 63;
    const int wav = tid >> 6;
    const int wm = wav >> 1, wn = wav & 1;
    const int fr = lane & 15;
    const int fks = (lane >> 4) << 3;

    f32x4 acc[2][2];
#pragma unroll
    for (int i = 0; i < 2; ++i)
#pragma unroll
        for (int j = 0; j < 2; ++j) acc[i][j] = (f32x4){0.f, 0.f, 0.f, 0.f};

#pragma unroll
    for (int kt = 0; kt < 256; kt += 32) {
        bf16x8 ah[2], al[2], bh[2], bl[2];
#pragma unroll
        for (int s = 0; s < 2; ++s) {
            ah[s] = *(const bf16x8*)&sAhi[(wm << 5) + (s << 4) + fr][kt + fks];
            al[s] = *(const bf16x8*)&sAlo[(wm << 5) + (s << 4) + fr][kt + fks];
            bh[s] = *(const bf16x8*)&sBhi[(wn << 5) + (s << 4) + fr][kt + fks];
            bl[s] = *(const bf16x8*)&sBlo[(wn << 5) + (s << 4) + fr][kt + fks];
        }
#pragma unroll
        for (int i = 0; i < 2; ++i)
#pragma unroll
            for (int j = 0; j < 2; ++j) {
                acc[i][j] = __builtin_amdgcn_mfma_f32_16x16x32_bf16(ah[i], bh[j], acc[i][j], 0, 0, 0);
                acc[i][j] = __builtin_amdgcn_mfma_f32_16x16x32_bf16(ah[i], bl[j], acc[i][j], 0, 0, 0);
                acc[i][j] = __builtin_amdgcn_mfma_f32_16x16x32_bf16(al[i], bh[j], acc[i][j], 0, 0, 0);
            }
    }

    const int rbase = (lane >> 4) << 2;
    if (!is_nt) {
#pragma unroll
        for (int i = 0; i < 2; ++i)
#pragma unroll
            for (int j = 0; j < 2; ++j) {
                const int gcol = n0 + (wn << 5) + (j << 4) + fr;
                const float bias = b1[gcol];
#pragma unroll
                for (int q = 0; q < 4; ++q) {
                    const int grow = m0 + (wm << 5) + (i << 4) + rbase + q;
                    float x = acc[i][j][q] + bias;
                    x = 1.0f - 2.0f * __builtin_amdgcn_rcpf(
                                          1.0f + __builtin_amdgcn_exp2f(C2F * x));
                    h1[(size_t)grow * 256 + gcol] = x;
                }
            }
    } else {
#pragma unroll
        for (int i = 0; i < 2; ++i)
#pragma unroll
            for (int j = 0; j < 2; ++j) {
                const int gcol = n0 + (wn << 5) + (j << 4) + fr;
#pragma unroll
                for (int q = 0; q < 4; ++q) {
                    const int grow = m0 + (wm << 5) + (i << 4) + rbase + q;
                    Wc[(size_t)grow * 256 + gcol] = acc[i][j][q];
                }
            }
        if ((blk & 3) == 0) {
            const int rr = tid >> 2;
            const int part = (tid & 3) << 6;
            const int grow = m0 + rr;
            const float* Ar = (grow < 256) ? &Wq[(size_t)grow * 256]
                                           : &Wk[(size_t)(grow - 256) * 256];
            float s = 0.f;
#pragma unroll
            for (int e = 0; e < 64; e += 4) {
                f4 a = *(const f4*)&Ar[part + e];
                f4 bv = *(const f4*)&b2[part + e];
                s += a[0] * bv[0] + a[1] * bv[1] + a[2] * bv[2] + a[3] * bv[3];
            }
            sred[rr][tid & 3] = s;
            __syncthreads();
            if (tid < 64) {
                float bias = sred[tid][0] + sred[tid][1] + sred[tid][2] + sred[tid][3];
                const int g2 = m0 + tid;
                bias += (g2 < 256) ? bq[g2] : bk[g2 - 256];
                bc[g2] = bias;
            }
        }
    }
}

// ---------------------------------------------------------------------------
// pairwise: per (b, i-tile, j-tile, h-chunk) block writes
//   Ep[chunk][b,i,j] = sum_{h in 64-chunk} v_h/(1+u_ih w_jh)
// 512 thr, 64x64 tile, ONE 64-h chunk per block (35 KB LDS).
// launch_bounds (512,4): allocator targets <=128 VGPR; with the observed ~64
// VGPR the HW co-schedules 4 blocks/CU (32 waves/CU).  (512,8) pinned VGPR=32
// and spilled 180 MB to scratch -- round-5 regression.
// ---------------------------------------------------------------------------
__global__ __launch_bounds__(512, 4) void pairwise_kernel(
    const float* __restrict__ uwb, const float* __restrict__ v,
    float* __restrict__ Ep) {
    __shared__ float sU[64][68];
    __shared__ float sW[64][68];
    __shared__ float sV[64];

    const int tid = threadIdx.x;
    const int bb = blockIdx.x;       // 1024 = (4b * 64 tiles) * 4 h-chunks
    const int hcs = bb & 3;          // h-chunk slice index
    const int hc = hcs << 6;
    const int tt = bb >> 2;
    const int b = tt >> 6;
    const int i0 = ((tt >> 3) & 7) << 6;
    const int j0 = (tt & 7) << 6;

    const float* ubase = uwb + (size_t)((b << 9) + i0) * 512 + hc;
    const float* wbase = uwb + (size_t)((b << 9) + j0) * 512 + 256 + hc;

    const int sr = tid >> 3;         // 0..63
    const int sc = (tid & 7) << 3;   // 0,8,..,56
    {
        f4 a0 = *(const f4*)&ubase[(size_t)sr * 512 + sc];
        f4 a1 = *(const f4*)&ubase[(size_t)sr * 512 + sc + 4];
        f4 b0 = *(const f4*)&wbase[(size_t)sr * 512 + sc];
        f4 b1 = *(const f4*)&wbase[(size_t)sr * 512 + sc + 4];
        *(f4*)&sU[sr][sc] = a0;
        *(f4*)&sU[sr][sc + 4] = a1;
        *(f4*)&sW[sr][sc] = b0;
        *(f4*)&sW[sr][sc + 4] = b1;
    }
    if (tid < 16) *(f4*)&sV[tid << 2] = *(const f4*)&v[hc + (tid << 2)];
    __syncthreads();

    const int ty = tid >> 5;   // 0..15: rows ty+16d
    const int tx = tid & 31;   // 0..31: cols tx+32e

    float acc[4][2];
#pragma unroll
    for (int d = 0; d < 4; ++d)
#pragma unroll
        for (int e = 0; e < 2; ++e) acc[d][e] = 0.f;

    const f2 one2 = (f2){1.f, 1.f};

#pragma unroll 4
    for (int h4 = 0; h4 < 64; h4 += 4) {
        f4 vv = *(const f4*)&sV[h4];
        f4 uu[4], ww[2];
#pragma unroll
        for (int d = 0; d < 4; ++d) uu[d] = *(const f4*)&sU[ty + (d << 4)][h4];
#pragma unroll
        for (int e = 0; e < 2; ++e) ww[e] = *(const f4*)&sW[tx + (e << 5)][h4];
#pragma unroll
        for (int d = 0; d < 4; ++d)
#pragma unroll
            for (int e = 0; e < 2; ++e) {
                f2 u01 = (f2){uu[d][0], uu[d][1]};
                f2 u23 = (f2){uu[d][2], uu[d][3]};
                f2 w01 = (f2){ww[e][0], ww[e][1]};
                f2 w23 = (f2){ww[e][2], ww[e][3]};
                f2 A01 = __builtin_elementwise_fma(u01, w01, one2);
                f2 A23 = __builtin_elementwise_fma(u23, w23, one2);
                float m01 = A01.x * A01.y;
                float t01 = fmaf(vv[0], A01.y, vv[1] * A01.x);
                acc[d][e] = fmaf(t01, __builtin_amdgcn_rcpf(m01), acc[d][e]);
                float m23 = A23.x * A23.y;
                float t23 = fmaf(vv[2], A23.y, vv[3] * A23.x);
                acc[d][e] = fmaf(t23, __builtin_amdgcn_rcpf(m23), acc[d][e]);
            }
    }

    float* ep = Ep + (size_t)hcs * 1048576 + (size_t)((b << 9) + i0) * 512 + j0;
#pragma unroll
    for (int d = 0; d < 4; ++d)
#pragma unroll
        for (int e = 0; e < 2; ++e)
            ep[(size_t)(ty + (d << 4)) * 512 + tx + (e << 5)] = acc[d][e];
}

// out[b,i,j] = Sv - sum_s Ep_s[b,i,j] - sum_s Ep_s[b,j,i]
__global__ __launch_bounds__(256) void sym_kernel(const float* __restrict__ Ep,
                                                  const float* __restrict__ v,
                                                  float* __restrict__ out) {
    __shared__ float t1[64][65];
    __shared__ float t2[64][65];
    __shared__ float red[4];

    const int tid = threadIdx.x;
    const int lane = tid & 63, wv = tid >> 6;

    float x = v[tid];
#pragma unroll
    for (int o = 32; o > 0; o >>= 1) x += __shfl_xor(x, o, 64);
    if (lane == 0) red[wv] = x;

    const int bb = blockIdx.x;
    const int b = bb >> 6;
    const int i0 = ((bb >> 3) & 7) << 6;
    const int j0 = (bb & 7) << 6;

    for (int idx = tid; idx < 4096; idx += 256) {
        const int r = idx >> 6, c = idx & 63;
        const size_t o1 = (size_t)((b << 9) + i0 + r) * 512 + j0 + c;
        const size_t o2 = (size_t)((b << 9) + j0 + r) * 512 + i0 + c;
        t1[r][c] = (Ep[o1] + Ep[o1 + 1048576]) +
                   (Ep[o1 + 2097152] + Ep[o1 + 3145728]);
        t2[r][c] = (Ep[o2] + Ep[o2 + 1048576]) +
                   (Ep[o2 + 2097152] + Ep[o2 + 3145728]);
    }
    __syncthreads();
    const float Sv = red[0] + red[1] + red[2] + red[3];
    for (int idx = tid; idx < 4096; idx += 256) {
        const int r = idx >> 6, c = idx & 63;
        out[(size_t)((b << 9) + i0 + r) * 512 + j0 + c] = Sv - (t1[r][c] + t2[c][r]);
    }
}

extern "C" void kernel_launch(void* const* d_in, const int* in_sizes, int n_in,
                              void* d_out, int out_size, void* d_ws, size_t ws_size,
                              hipStream_t stream) {
    const float* X  = (const float*)d_in[0];
    // d_in[1] = Y (unused)
    const float* W1 = (const float*)d_in[2];
    const float* b1 = (const float*)d_in[3];
    const float* W2 = (const float*)d_in[4];
    const float* b2 = (const float*)d_in[5];
    const float* Wq = (const float*)d_in[6];
    const float* bq = (const float*)d_in[7];
    const float* Wk = (const float*)d_in[8];
    const float* bk = (const float*)d_in[9];
    const float* v  = (const float*)d_in[10];
    // d_in[11] = k (unused)

    float* ws  = (float*)d_ws;
    float* h1  = ws;                 // 2048*256 = 524288 f
    float* uwb = ws + 524288;        // 2048*512 = 1048576 f
    float* Wc  = ws + 1572864;       // 512*256  = 131072 f
    float* bc  = ws + 1703936;       // 512 f
    float* Ep  = ws + 1704448;       // 4*1048576 f
    float* out = (float*)d_out;

    // fused: h1 = tanh(X@W1^T+b1)  and  Wc = [Wq;Wk]@W2, bc = [..]@b2 + bias
    gemm_stage1<<<160, 256, 0, stream>>>(X, W1, b1, Wq, Wk, W2, b2, bq, bk,
                                         h1, Wc, bc);
    // uwb[:, :256] = min(exp2(C2*Q),1e4), uwb[:, 256:] = min(exp2(C2*K),1e4)
    gemm_fullk<2><<<dim3(32, 8), 256, 0, stream>>>(h1, Wc, Wc + 65536, bc,
                                                   bc + 256, uwb, 512);
    // Ep[hc][b,i,j] = sum_{h in chunk} v_h/(1+u w)
    pairwise_kernel<<<1024, 512, 0, stream>>>(uwb, v, Ep);
    // out = Sv - sum(Ep) - sum(Ep)^T
    sym_kernel<<<256, 256, 0, stream>>>(Ep, v, out);
}